// Round 1
// baseline (134.017 us; speedup 1.0000x reference)
//
#include <hip/hip_runtime.h>

// Rips 1-skeleton Euler characteristic curve.
// B=4096 points in [0,1]^3; bins t = clip(ceil(d*31.5), 0, 63); out = cumsum.
// All pairwise d <= sqrt(3) < t_max=2 => every pair is an edge.

#define B_PTS 4096
#define STEPS 64
#define SCALE_F 31.5f
#define K1_BLOCKS 512
#define K1_THREADS 256
#define WAVES_PER_BLOCK (K1_THREADS / 64)

__global__ __launch_bounds__(K1_THREADS) void rips_pair_hist(
    const float* __restrict__ x, int* __restrict__ ws_hist) {
    // Per-wave replicated histogram: atomics only collide within a wave.
    __shared__ int hist[WAVES_PER_BLOCK][STEPS];

    const int tid = threadIdx.x;
    const int wave = tid >> 6;

    for (int k = tid; k < WAVES_PER_BLOCK * STEPS; k += K1_THREADS)
        (&hist[0][0])[k] = 0;
    __syncthreads();

    const int G = gridDim.x;
    for (int i = blockIdx.x; i < B_PTS; i += G) {
        const float xi = x[3 * i + 0];
        const float yi = x[3 * i + 1];
        const float zi = x[3 * i + 2];
        for (int j = i + 1 + tid; j < B_PTS; j += K1_THREADS) {
            const float dx = xi - x[3 * j + 0];
            const float dy = yi - x[3 * j + 1];
            const float dz = zi - x[3 * j + 2];
            const float d2 = dx * dx + dy * dy + dz * dz;
            const float d = sqrtf(d2);
            int t = (int)ceilf(d * SCALE_F);
            t = t < 0 ? 0 : (t > STEPS - 1 ? STEPS - 1 : t);
            atomicAdd(&hist[wave][t], 1);
        }
    }
    __syncthreads();

    if (tid < STEPS) {
        int s = 0;
#pragma unroll
        for (int w = 0; w < WAVES_PER_BLOCK; ++w) s += hist[w][tid];
        ws_hist[blockIdx.x * STEPS + tid] = s;
    }
}

__global__ __launch_bounds__(64) void rips_finalize(
    const int* __restrict__ ws_hist, int nblocks, float* __restrict__ out) {
    __shared__ int cnt[STEPS];
    const int tid = threadIdx.x;  // 64 threads, one wave

    int s = 0;
    for (int b = 0; b < nblocks; ++b) s += ws_hist[b * STEPS + tid];
    cnt[tid] = s;
    __syncthreads();
    if (tid == 0) {
        int acc = 0;
        for (int k = 0; k < STEPS; ++k) { acc += cnt[k]; cnt[k] = acc; }
    }
    __syncthreads();
    // ecc[0] = +B (all vertices at filtration 0, bin 0), each edge -1 at its bin.
    out[tid] = (float)B_PTS - (float)cnt[tid];
}

extern "C" void kernel_launch(void* const* d_in, const int* in_sizes, int n_in,
                              void* d_out, int out_size, void* d_ws, size_t ws_size,
                              hipStream_t stream) {
    const float* x = (const float*)d_in[0];
    float* out = (float*)d_out;
    int* ws_hist = (int*)d_ws;

    int G = K1_BLOCKS;
    const size_t need = (size_t)G * STEPS * sizeof(int);
    if (ws_size < need) G = (int)(ws_size / (STEPS * sizeof(int)));

    rips_pair_hist<<<G, K1_THREADS, 0, stream>>>(x, ws_hist);
    rips_finalize<<<1, 64, 0, stream>>>(ws_hist, G, out);
}

// Round 2
// 75.255 us; speedup vs baseline: 1.7808x; 1.7808x over previous
//
#include <hip/hip_runtime.h>

// Rips 1-skeleton Euler characteristic curve.
// B=4096 points in [0,1]^3; bin t = clip(ceil(d*31.5), 0, 63); out = B - cumsum(edge_hist).
// All pairwise d <= sqrt(3) < t_max=2 => every pair is an edge.

#define B_PTS 4096
#define STEPS 64
#define SCALE_F 31.5f
#define G_BLOCKS 768      // 3 blocks/CU at 49 KB LDS each
#define NTHREADS 256
#define NWAVES (NTHREADS / 64)

__global__ __launch_bounds__(NTHREADS) void rips_pair_hist(
    const float* __restrict__ x, int* __restrict__ g_hist) {
    __shared__ float pts[B_PTS * 3];      // 48 KB: all points, packed xyz
    __shared__ int hist[NWAVES][STEPS];   // per-wave replicated histogram

    const int tid = threadIdx.x;
    const int wave = tid >> 6;

    // Stage all points global -> LDS with float4 loads (12288 floats).
    {
        const float4* x4 = (const float4*)x;
        float4* p4 = (float4*)pts;
        for (int k = tid; k < (B_PTS * 3) / 4; k += NTHREADS) p4[k] = x4[k];
    }
    for (int k = tid; k < NWAVES * STEPS; k += NTHREADS) (&hist[0][0])[k] = 0;
    __syncthreads();

    // Grid-stride over rows i; threads cover columns j > i from LDS.
    for (int i = blockIdx.x; i < B_PTS - 1; i += G_BLOCKS) {
        const float xi = pts[3 * i + 0];
        const float yi = pts[3 * i + 1];
        const float zi = pts[3 * i + 2];
        for (int j = i + 1 + tid; j < B_PTS; j += NTHREADS) {
            const float dx = xi - pts[3 * j + 0];
            const float dy = yi - pts[3 * j + 1];
            const float dz = zi - pts[3 * j + 2];
            const float d2 = dx * dx + dy * dy + dz * dz;
            const float d = __builtin_amdgcn_sqrtf(d2);  // raw v_sqrt_f32
            int t = (int)ceilf(d * SCALE_F);             // >= 0 since d >= 0
            t = t > STEPS - 1 ? STEPS - 1 : t;
            atomicAdd(&hist[wave][t], 1);
        }
    }
    __syncthreads();

    // Flush block histogram with 64 device-scope atomics (one wave).
    if (tid < STEPS) {
        int s = 0;
#pragma unroll
        for (int w = 0; w < NWAVES; ++w) s += hist[w][tid];
        if (s) atomicAdd(&g_hist[tid], s);
    }
}

__global__ __launch_bounds__(64) void rips_finalize(
    const int* __restrict__ g_hist, float* __restrict__ out) {
    __shared__ int cnt[STEPS];
    const int tid = threadIdx.x;  // one wave
    cnt[tid] = g_hist[tid];
    __syncthreads();
    if (tid == 0) {
        int acc = 0;
        for (int k = 0; k < STEPS; ++k) { acc += cnt[k]; cnt[k] = acc; }
    }
    __syncthreads();
    // +B_PTS vertices at bin 0, -1 per edge at its bin, cumsum'd.
    out[tid] = (float)B_PTS - (float)cnt[tid];
}

extern "C" void kernel_launch(void* const* d_in, const int* in_sizes, int n_in,
                              void* d_out, int out_size, void* d_ws, size_t ws_size,
                              hipStream_t stream) {
    const float* x = (const float*)d_in[0];
    float* out = (float*)d_out;
    int* g_hist = (int*)d_ws;  // 64 ints

    hipMemsetAsync(g_hist, 0, STEPS * sizeof(int), stream);
    rips_pair_hist<<<G_BLOCKS, NTHREADS, 0, stream>>>(x, g_hist);
    rips_finalize<<<1, 64, 0, stream>>>(g_hist, out);
}